// Round 6
// baseline (254.326 us; speedup 1.0000x reference)
//
#include <hip/hip_runtime.h>
#include <stdint.h>

#define DIM   384
#define NH    8
#define HD    48
#define NTOK  4096
#define KDIM  384
// 1/sqrt(48) * log2(e): q pre-scaled so softmax uses exp2 (v_exp_f32) directly
#define SCALEL2E 0.20823509610f

typedef float  f32x4   __attribute__((ext_vector_type(4)));
typedef float  f32x16  __attribute__((ext_vector_type(16)));
typedef __bf16 bf16x8  __attribute__((ext_vector_type(8)));

#if __has_builtin(__builtin_amdgcn_exp2f)
#define EXP2F(x) __builtin_amdgcn_exp2f(x)
#else
#define EXP2F(x) exp2f(x)
#endif

__device__ __forceinline__ unsigned short f2bf(float f) {
  union { float f; unsigned int u; } c; c.f = f;
  unsigned int r = (c.u + 0x7FFFu + ((c.u >> 16) & 1u)) >> 16;  // RNE
  return (unsigned short)r;
}
__device__ __forceinline__ float bf2f(unsigned short h) {
  union { unsigned int u; float f; } c; c.u = ((unsigned int)h) << 16;
  return c.f;
}

// ws layout (bytes):
//   x_bf @ 0        : 8192*384*2     = 6,291,456
//   w_bf @ 6291456  : 1152*384*2     =   884,736
//   qc   @ 7176192  : 2*8*4096*48*2  = 6,291,456   [b,h,n,48] bf16, scaled by SCALEL2E
//   kc   @ 13467648 : 6,291,456                     [b,h,n,48] bf16
//   v_t  @ 19759104 : 2*384*4096*2   = 6,291,456   [b,c,n] bf16
// total ~26.1 MB  (kc overfetch spills into v_t head — allocated, harmless)

// ---------------- prep: f32->bf16 conversions -------------------------------
__global__ void prep_kernel(const float* __restrict__ x, const float* __restrict__ w,
                            unsigned short* __restrict__ x_bf,
                            unsigned short* __restrict__ w_bf) {
  int tid = blockIdx.x * blockDim.x + threadIdx.x;
  int stride = gridDim.x * blockDim.x;
  for (int i = tid; i < 786432; i += stride) {
    float4 v = ((const float4*)x)[i];
    ushort4 o;
    o.x = f2bf(v.x); o.y = f2bf(v.y); o.z = f2bf(v.z); o.w = f2bf(v.w);
    ((ushort4*)x_bf)[i] = o;
  }
  for (int i = tid; i < 110592; i += stride) {
    float4 v = ((const float4*)w)[i];
    ushort4 o;
    o.x = f2bf(v.x); o.y = f2bf(v.y); o.z = f2bf(v.z); o.w = f2bf(v.w);
    ((ushort4*)w_bf)[i] = o;
  }
}

// ---------------- QKV GEMM: 8192 x 1152, K=384, 128x64 tiles ---------------
__global__ __launch_bounds__(256) void qkv_gemm(
    const unsigned short* __restrict__ A,    // x_bf [8192][384]
    const unsigned short* __restrict__ Bw,   // w_bf [1152][384]  (B^T)
    const float* __restrict__ bias,          // [1152]
    unsigned short* __restrict__ qc,
    unsigned short* __restrict__ kc,
    unsigned short* __restrict__ v_t) {
  __shared__ unsigned short ldsA[128 * 32];
  __shared__ unsigned short ldsB[64 * 32];
  __shared__ unsigned short ebuf[64 * 72];   // epilogue transpose buffer
  const int tid = threadIdx.x;
  const int wv = tid >> 6, ln = tid & 63;
  const int lrow = ln & 15, lq = ln >> 4;
  const int m0 = blockIdx.x * 128;
  const int n0 = blockIdx.y * 64;
  const int wm = (wv >> 1) * 64, wn = (wv & 1) * 32;

  f32x4 acc[4][2];
#pragma unroll
  for (int mi = 0; mi < 4; ++mi)
#pragma unroll
    for (int ni = 0; ni < 2; ++ni)
#pragma unroll
      for (int r = 0; r < 4; ++r) acc[mi][ni][r] = 0.f;

  for (int k0 = 0; k0 < KDIM; k0 += 32) {
    __syncthreads();
#pragma unroll
    for (int j = 0; j < 2; ++j) {
      int r16 = wv * 2 + j;
      const unsigned short* ga = A + (size_t)(m0 + r16 * 16 + (ln >> 2)) * KDIM
                                   + k0 + (ln & 3) * 8;
      __builtin_amdgcn_global_load_lds(
          (const __attribute__((address_space(1))) void*)ga,
          (__attribute__((address_space(3))) void*)&ldsA[r16 * 512], 16, 0, 0);
    }
    const unsigned short* gb = Bw + (size_t)(n0 + wv * 16 + (ln >> 2)) * KDIM
                                  + k0 + (ln & 3) * 8;
    __builtin_amdgcn_global_load_lds(
        (const __attribute__((address_space(1))) void*)gb,
        (__attribute__((address_space(3))) void*)&ldsB[wv * 512], 16, 0, 0);
    __syncthreads();
    bf16x8 af[4], bfv[2];
#pragma unroll
    for (int mi = 0; mi < 4; ++mi)
      af[mi] = *(const bf16x8*)&ldsA[(wm + mi * 16 + lrow) * 32 + lq * 8];
#pragma unroll
    for (int ni = 0; ni < 2; ++ni)
      bfv[ni] = *(const bf16x8*)&ldsB[(wn + ni * 16 + lrow) * 32 + lq * 8];
#pragma unroll
    for (int mi = 0; mi < 4; ++mi)
#pragma unroll
      for (int ni = 0; ni < 2; ++ni)
        acc[mi][ni] = __builtin_amdgcn_mfma_f32_16x16x32_bf16(
            af[mi], bfv[ni], acc[mi][ni], 0, 0, 0);
  }

  // ---- epilogue: C-tile half -> ebuf (bf16) -> 16B vector stores ----
  const int region = (n0 >= 768) ? 2 : (n0 >= 384 ? 1 : 0);   // q/k/v, block-uniform
  const float scl = (region == 0) ? SCALEL2E : 1.0f;
  const float bias0 = bias[n0 + wn + lrow];
  const float bias1 = bias[n0 + wn + 16 + lrow];

#pragma unroll
  for (int half = 0; half < 2; ++half) {
    __syncthreads();
    if ((wv >> 1) == half) {
#pragma unroll
      for (int mi = 0; mi < 4; ++mi)
#pragma unroll
        for (int ni = 0; ni < 2; ++ni)
#pragma unroll
          for (int r = 0; r < 4; ++r) {
            int row = mi * 16 + lq * 4 + r;        // 0..63 within half
            int col = wn + ni * 16 + lrow;         // 0..63
            float val = (acc[mi][ni][r] + (ni ? bias1 : bias0)) * scl;
            ebuf[row * 72 + col] = f2bf(val);
          }
    }
    __syncthreads();
    if (region < 2) {
      unsigned short* dst = (region == 0) ? qc : kc;
      const int obase = n0 - region * 384;
#pragma unroll
      for (int i = 0; i < 2; ++i) {
        int id = tid + i * 256;                    // 0..511 = 64 rows x 8 chunks
        int row = id >> 3, cc = id & 7;
        uint4 val = *(const uint4*)&ebuf[row * 72 + cc * 8];
        int nrow = m0 + half * 64 + row;
        int b = nrow >> 12, nn = nrow & 4095;
        int o = obase + cc * 8;
        int h = o / 48, d = o - h * 48;            // 8-chunk never straddles h
        *(uint4*)&dst[((size_t)(b * 8 + h) * NTOK + nn) * HD + d] = val;
      }
    } else {
#pragma unroll
      for (int i = 0; i < 2; ++i) {
        int id = tid + i * 256;                    // 0..511 = 64 cols x 8 row-chunks
        int col = id & 63, rc = id >> 6;
        int r0 = rc * 8;
        union { unsigned short s[8]; uint4 u; } pk;
#pragma unroll
        for (int j = 0; j < 8; ++j)
          pk.s[j] = ebuf[(r0 + j) * 72 + col];
        int nrow = m0 + half * 64 + r0;
        int b = nrow >> 12;
        int o = n0 - 768 + col;
        *(uint4*)&v_t[((size_t)(b * DIM + o)) * NTOK + (nrow & 4095)] = pk.u;
      }
    }
  }
}

// ---------------- LePE: depthwise 3x3, coalesced output (writes out base) --
__global__ __launch_bounds__(256) void lepe_kernel(
    const unsigned short* __restrict__ v_t,
    const float* __restrict__ lw, const float* __restrict__ lb,
    float* __restrict__ out) {
  __shared__ __align__(16) unsigned short pl[16 * 648];
  const int cg = blockIdx.x;      // 0..23
  const int sy = blockIdx.y;      // 0..7
  const int b  = blockIdx.z;      // 0..1
  const int t = threadIdx.x;
  const int y0 = sy * 8;
#pragma unroll
  for (int i = 0; i < 5; ++i) {
    int id = t + i * 256;                      // 0..1279
    int c = id / 80, rem = id - c * 80;
    int row = rem >> 3, cx = rem & 7;
    int y = y0 - 1 + row;
    uint4 val = make_uint4(0u, 0u, 0u, 0u);
    if (y >= 0 && y < 64)
      val = *(const uint4*)(v_t + ((size_t)(b * DIM + cg * 16 + c)) * NTOK + y * 64 + cx * 8);
    *(uint4*)&pl[c * 648 + row * 64 + cx * 8] = val;
  }
  __syncthreads();
  const int c = t & 15, pg = t >> 4;
  const int cglob = cg * 16 + c;
  float w[9];
#pragma unroll
  for (int j = 0; j < 9; ++j) w[j] = lw[cglob * 9 + j];
  const float bias = lb[cglob];
  const unsigned short* base = &pl[c * 648];
  for (int i = 0; i < 32; ++i) {
    int p = pg * 32 + i;
    int lr = p >> 6, x = p & 63;
    float acc = bias;
#pragma unroll
    for (int ky = 0; ky < 3; ++ky)
#pragma unroll
      for (int kx = 0; kx < 3; ++kx) {
        int xx = x + kx - 1;
        if (xx >= 0 && xx < 64)
          acc += w[ky * 3 + kx] * bf2f(base[(lr + ky) * 64 + xx]);
      }
    out[((size_t)(b * NTOK + sy * 512 + p)) * DIM + cglob] = acc;
  }
}

// ---------------- flash attention: no shuffles, register-prefetch staging --
// block 256 = 2 kt-halves x 2 q-waves x 2 Q-sets (128 qrows/block).
// S^T = K*Q^T (lane owns its qrow). PV key order is PERMUTED per MFMA slot
// (k-slot j -> key 16u+4hh+(j&3)+8(j>>2)) so the A-frag is 4 consecutive P32
// words (no lane exchange) and B-frags are 2x ds_read_b64 from V.
// K stride 72 / V stride 68: bank-conflict-free (b128 & b64 floors).
// V row 48 = ones -> PV col 48 accumulates lsum for free.
__global__ __launch_bounds__(256, 2) void attn_kernel(
    const unsigned short* __restrict__ qc,
    const unsigned short* __restrict__ kcg,
    const unsigned short* __restrict__ v_t,
    float* __restrict__ out) {
  __shared__ __align__(16) char smem[36864];
  unsigned short* Kl = (unsigned short*)smem;            // [2][64*72]
  unsigned short* Vl = (unsigned short*)(smem + 18432);  // [2][64*68]
  float* Lsum = (float*)(smem + 35840);                  // [2][128]
  float* Ol   = (float*)smem;                            // alias [128][48] epilogue

  const int tid = threadIdx.x;
  const int wv = tid >> 6, ln = tid & 63;
  const int kh = wv >> 1;          // kt-half
  const int wq = wv & 1;           // qrow group within each set
  const int l31 = ln & 31, hh = ln >> 5;
  const int th = tid & 127;        // thread id within half
  const int qb = blockIdx.x;       // 0..31  (128 qrows each)
  const int bh = blockIdx.y;
  const int b = bh >> 3, hd = bh & 7;

  unsigned short* Kh = Kl + kh * 4608;
  unsigned short* Vh = Vl + kh * 4352;

  // staging offsets (loop-invariant). K: 64 rows x 8 chunks (2 overfetch).
  int kwo[4], kgo[4], vwo[3], vgo[3];
#pragma unroll
  for (int i = 0; i < 4; ++i) {
    int idx = th + i * 128;                // 0..511
    int r = idx >> 3, cc = idx & 7;
    kwo[i] = r * 72 + cc * 8;
    kgo[i] = r * 48 + cc * 8;              // cc>=6 overfetch: never read back
  }
#pragma unroll
  for (int i = 0; i < 3; ++i) {
    int idx = th + i * 128;                // 0..383
    int vd = idx >> 3, vc = idx & 7;       // V: 48 rows x 8 chunks
    vwo[i] = vd * 68 + vc * 8;
    vgo[i] = vd * 4096 + vc * 8;
  }

  // V ones-row (row 48): PV output col 48 = sum_k P = lsum. Never re-written.
  if (th < 8) {
    uint4 one4 = make_uint4(0x3F803F80u, 0x3F803F80u, 0x3F803F80u, 0x3F803F80u);
    *(uint4*)&Vh[48 * 68 + th * 8] = one4;
  }

  // Q fragments: 2 sets x (lane's own qrow, 3 hd-chunks of 16)
  bf16x8 Qf[2][3];
#pragma unroll
  for (int set = 0; set < 2; ++set) {
    const int qrow = qb * 128 + set * 64 + wq * 32 + l31;
    const unsigned short* qp = qc + ((size_t)bh * NTOK + qrow) * HD + hh * 8;
#pragma unroll
    for (int hs = 0; hs < 3; ++hs)
      Qf[set][hs] = *(const bf16x8*)(qp + hs * 16);
  }

  f32x16 Oacc[2][2];
#pragma unroll
  for (int set = 0; set < 2; ++set)
#pragma unroll
    for (int dc = 0; dc < 2; ++dc)
#pragma unroll
      for (int r = 0; r < 16; ++r) Oacc[set][dc][r] = 0.f;

  const unsigned short* kbase = kcg + (size_t)bh * NTOK * HD;
  const unsigned short* vbase = v_t + ((size_t)b * DIM + hd * HD) * NTOK;

  // prologue: prefetch first tile into registers
  uint4 kreg[4], vreg[3];
  {
    const unsigned short* kg = kbase + (size_t)(kh * 32) * 64 * HD;
    const unsigned short* vg = vbase + (kh * 32) * 64;
#pragma unroll
    for (int i = 0; i < 4; ++i) kreg[i] = *(const uint4*)(kg + kgo[i]);
#pragma unroll
    for (int i = 0; i < 3; ++i) vreg[i] = *(const uint4*)(vg + vgo[i]);
  }

  for (int it = 0; it < 32; ++it) {
    __syncthreads();                       // prev compute done reading LDS
#pragma unroll
    for (int i = 0; i < 4; ++i) *(uint4*)&Kh[kwo[i]] = kreg[i];
#pragma unroll
    for (int i = 0; i < 3; ++i) *(uint4*)&Vh[vwo[i]] = vreg[i];
    {                                      // issue next-tile loads (hidden under compute)
      int ktn = kh * 32 + ((it + 1) & 31); // wraps on last iter: in-bounds, same work
      const unsigned short* kg = kbase + (size_t)ktn * 64 * HD;
      const unsigned short* vg = vbase + ktn * 64;
#pragma unroll
      for (int i = 0; i < 4; ++i) kreg[i] = *(const uint4*)(kg + kgo[i]);
#pragma unroll
      for (int i = 0; i < 3; ++i) vreg[i] = *(const uint4*)(vg + vgo[i]);
    }
    __syncthreads();                       // LDS tile visible

#pragma unroll
    for (int C = 0; C < 2; ++C) {
      // S^T = K * Q^T for both Q sets (3 K=16 steps, shared kf)
      f32x16 sA, sB;
#pragma unroll
      for (int r = 0; r < 16; ++r) { sA[r] = 0.f; sB[r] = 0.f; }
      const unsigned short* kr = &Kh[(C * 32 + l31) * 72 + hh * 8];
#pragma unroll
      for (int hs = 0; hs < 3; ++hs) {
        bf16x8 kf = *(const bf16x8*)(kr + hs * 16);
        sA = __builtin_amdgcn_mfma_f32_32x32x16_bf16(kf, Qf[0][hs], sA, 0, 0, 0);
        sB = __builtin_amdgcn_mfma_f32_32x32x16_bf16(kf, Qf[1][hs], sB, 0, 0, 0);
      }
      // exp2 + pack pairs: P32[set][t8] = regs (2t8, 2t8+1) as bf16x2
      unsigned int PA[8], PB[8];
#pragma unroll
      for (int t8 = 0; t8 < 8; ++t8) {
        float a0 = EXP2F(sA[2 * t8]);
        float a1 = EXP2F(sA[2 * t8 + 1]);
        PA[t8] = __builtin_amdgcn_perm(__float_as_uint(a1), __float_as_uint(a0),
                                       0x07060302u);
        float b0 = EXP2F(sB[2 * t8]);
        float b1 = EXP2F(sB[2 * t8 + 1]);
        PB[t8] = __builtin_amdgcn_perm(__float_as_uint(b1), __float_as_uint(b0),
                                       0x07060302u);
      }
      // O += P*V with permuted key order: A = 4 consecutive P32 words;
      // B slot j -> key C*32 + 16u + 4hh + (j&3) + 8(j>>2)  (groups g, g+2)
#pragma unroll
      for (int u = 0; u < 2; ++u) {
        union { unsigned int w[4]; bf16x8 v; } pa0, pa1;
#pragma unroll
        for (int w4 = 0; w4 < 4; ++w4) {
          pa0.w[w4] = PA[4 * u + w4];
          pa1.w[w4] = PB[4 * u + w4];
        }
        const int goff = (C * 8 + 4 * u + hh) * 4;   // group start (shorts)
#pragma unroll
        for (int dc = 0; dc < 2; ++dc) {
          const int vrow = dc * 32 + l31;  // row 48 = ones (lsum); 49-63 discarded
          const unsigned short* vrp = &Vh[vrow * 68 + goff];
          union { uint2 x[2]; bf16x8 v; } vf;
          vf.x[0] = *(const uint2*)(vrp);
          vf.x[1] = *(const uint2*)(vrp + 8);        // group g+2
          Oacc[0][dc] = __builtin_amdgcn_mfma_f32_32x32x16_bf16(
              pa0.v, vf.v, Oacc[0][dc], 0, 0, 0);
          Oacc[1][dc] = __builtin_amdgcn_mfma_f32_32x32x16_bf16(
              pa1.v, vf.v, Oacc[1][dc], 0, 0, 0);
        }
      }
    }
  }

  // ---- epilogue: combine kt-halves through LDS, normalize, out += ----
  __syncthreads();
  if (l31 == 16) {
#pragma unroll
    for (int set = 0; set < 2; ++set)
#pragma unroll
      for (int r = 0; r < 16; ++r) {
        int qrb = set * 64 + wq * 32 + (r & 3) + 8 * (r >> 2) + 4 * hh;
        Lsum[kh * 128 + qrb] = Oacc[set][1][r];
      }
  }
  if (kh == 1) {
#pragma unroll
    for (int set = 0; set < 2; ++set)
#pragma unroll
      for (int r = 0; r < 16; ++r) {
        int qrb = set * 64 + wq * 32 + (r & 3) + 8 * (r >> 2) + 4 * hh;
        Ol[qrb * 48 + l31] = Oacc[set][0][r];
        if (l31 < 16) Ol[qrb * 48 + 32 + l31] = Oacc[set][1][r];
      }
  }
  __syncthreads();
  if (kh == 0) {
#pragma unroll
    for (int set = 0; set < 2; ++set)
#pragma unroll
      for (int r = 0; r < 16; ++r) {
        int qrb = set * 64 + wq * 32 + (r & 3) + 8 * (r >> 2) + 4 * hh;
        float linv = 1.0f / (Lsum[qrb] + Lsum[128 + qrb]);
        float* op = out + ((size_t)(b * NTOK + qb * 128 + qrb)) * DIM + hd * HD;
        op[l31] += (Oacc[set][0][r] + Ol[qrb * 48 + l31]) * linv;
        if (l31 < 16)
          op[32 + l31] += (Oacc[set][1][r] + Ol[qrb * 48 + 32 + l31]) * linv;
      }
  }
}

// ---------------------------------------------------------------------------
extern "C" void kernel_launch(void* const* d_in, const int* in_sizes, int n_in,
                              void* d_out, int out_size, void* d_ws, size_t ws_size,
                              hipStream_t stream) {
  const float* x      = (const float*)d_in[0];
  const float* qkv_w  = (const float*)d_in[1];
  const float* qkv_b  = (const float*)d_in[2];
  const float* lepe_w = (const float*)d_in[3];
  const float* lepe_b = (const float*)d_in[4];

  char* ws = (char*)d_ws;
  unsigned short* x_bf = (unsigned short*)(ws);
  unsigned short* w_bf = (unsigned short*)(ws + 6291456);
  unsigned short* qcp  = (unsigned short*)(ws + 7176192);
  unsigned short* kcp  = (unsigned short*)(ws + 13467648);
  unsigned short* v_t  = (unsigned short*)(ws + 19759104);
  float* out = (float*)d_out;

  prep_kernel<<<1024, 256, 0, stream>>>(x, qkv_w, x_bf, w_bf);
  qkv_gemm<<<dim3(64, 18), 256, 0, stream>>>(x_bf, w_bf, qkv_b, qcp, kcp, v_t);
  lepe_kernel<<<dim3(24, 8, 2), 256, 0, stream>>>(v_t, lepe_w, lepe_b, out);
  attn_kernel<<<dim3(32, 16), 256, 0, stream>>>(qcp, kcp, v_t, out);
}

// Round 7
// 188.448 us; speedup vs baseline: 1.3496x; 1.3496x over previous
//
#include <hip/hip_runtime.h>
#include <stdint.h>

#define DIM   384
#define NH    8
#define HD    48
#define NTOK  4096
#define KDIM  384
// 1/sqrt(48) * log2(e): q pre-scaled so softmax uses exp2 (v_exp_f32) directly
#define SCALEL2E 0.20823509610f

typedef float  f32x4   __attribute__((ext_vector_type(4)));
typedef float  f32x16  __attribute__((ext_vector_type(16)));
typedef __bf16 bf16x8  __attribute__((ext_vector_type(8)));

#if __has_builtin(__builtin_amdgcn_exp2f)
#define EXP2F(x) __builtin_amdgcn_exp2f(x)
#else
#define EXP2F(x) exp2f(x)
#endif

__device__ __forceinline__ unsigned short f2bf(float f) {
  union { float f; unsigned int u; } c; c.f = f;
  unsigned int r = (c.u + 0x7FFFu + ((c.u >> 16) & 1u)) >> 16;  // RNE
  return (unsigned short)r;
}
__device__ __forceinline__ float bf2f(unsigned short h) {
  union { unsigned int u; float f; } c; c.u = ((unsigned int)h) << 16;
  return c.f;
}

// ws layout (bytes):
//   x_bf @ 0        : 8192*384*2     = 6,291,456
//   w_bf @ 6291456  : 1152*384*2     =   884,736
//   qc   @ 7176192  : 2*8*4096*48*2  = 6,291,456   [b,h,n,48] bf16, scaled by SCALEL2E
//   kc   @ 13467648 : 6,291,456                     [b,h,n,48] bf16
//   v_t  @ 19759104 : 2*384*4096*2   = 6,291,456   [b,c,n] bf16
// total ~26.1 MB  (kc overfetch spills into v_t head — allocated, harmless)

// ---------------- prep: f32->bf16 conversions -------------------------------
__global__ void prep_kernel(const float* __restrict__ x, const float* __restrict__ w,
                            unsigned short* __restrict__ x_bf,
                            unsigned short* __restrict__ w_bf) {
  int tid = blockIdx.x * blockDim.x + threadIdx.x;
  int stride = gridDim.x * blockDim.x;
  for (int i = tid; i < 786432; i += stride) {
    float4 v = ((const float4*)x)[i];
    ushort4 o;
    o.x = f2bf(v.x); o.y = f2bf(v.y); o.z = f2bf(v.z); o.w = f2bf(v.w);
    ((ushort4*)x_bf)[i] = o;
  }
  for (int i = tid; i < 110592; i += stride) {
    float4 v = ((const float4*)w)[i];
    ushort4 o;
    o.x = f2bf(v.x); o.y = f2bf(v.y); o.z = f2bf(v.z); o.w = f2bf(v.w);
    ((ushort4*)w_bf)[i] = o;
  }
}

// ---------------- QKV GEMM: 8192 x 1152, K=384, 128x64 tiles ---------------
__global__ __launch_bounds__(256) void qkv_gemm(
    const unsigned short* __restrict__ A,    // x_bf [8192][384]
    const unsigned short* __restrict__ Bw,   // w_bf [1152][384]  (B^T)
    const float* __restrict__ bias,          // [1152]
    unsigned short* __restrict__ qc,
    unsigned short* __restrict__ kc,
    unsigned short* __restrict__ v_t) {
  __shared__ unsigned short ldsA[128 * 32];
  __shared__ unsigned short ldsB[64 * 32];
  __shared__ unsigned short ebuf[64 * 72];   // epilogue transpose buffer
  const int tid = threadIdx.x;
  const int wv = tid >> 6, ln = tid & 63;
  const int lrow = ln & 15, lq = ln >> 4;
  const int m0 = blockIdx.x * 128;
  const int n0 = blockIdx.y * 64;
  const int wm = (wv >> 1) * 64, wn = (wv & 1) * 32;

  f32x4 acc[4][2];
#pragma unroll
  for (int mi = 0; mi < 4; ++mi)
#pragma unroll
    for (int ni = 0; ni < 2; ++ni)
#pragma unroll
      for (int r = 0; r < 4; ++r) acc[mi][ni][r] = 0.f;

  for (int k0 = 0; k0 < KDIM; k0 += 32) {
    __syncthreads();
#pragma unroll
    for (int j = 0; j < 2; ++j) {
      int r16 = wv * 2 + j;
      const unsigned short* ga = A + (size_t)(m0 + r16 * 16 + (ln >> 2)) * KDIM
                                   + k0 + (ln & 3) * 8;
      __builtin_amdgcn_global_load_lds(
          (const __attribute__((address_space(1))) void*)ga,
          (__attribute__((address_space(3))) void*)&ldsA[r16 * 512], 16, 0, 0);
    }
    const unsigned short* gb = Bw + (size_t)(n0 + wv * 16 + (ln >> 2)) * KDIM
                                  + k0 + (ln & 3) * 8;
    __builtin_amdgcn_global_load_lds(
        (const __attribute__((address_space(1))) void*)gb,
        (__attribute__((address_space(3))) void*)&ldsB[wv * 512], 16, 0, 0);
    __syncthreads();
    bf16x8 af[4], bfv[2];
#pragma unroll
    for (int mi = 0; mi < 4; ++mi)
      af[mi] = *(const bf16x8*)&ldsA[(wm + mi * 16 + lrow) * 32 + lq * 8];
#pragma unroll
    for (int ni = 0; ni < 2; ++ni)
      bfv[ni] = *(const bf16x8*)&ldsB[(wn + ni * 16 + lrow) * 32 + lq * 8];
#pragma unroll
    for (int mi = 0; mi < 4; ++mi)
#pragma unroll
      for (int ni = 0; ni < 2; ++ni)
        acc[mi][ni] = __builtin_amdgcn_mfma_f32_16x16x32_bf16(
            af[mi], bfv[ni], acc[mi][ni], 0, 0, 0);
  }

  // ---- epilogue: C-tile half -> ebuf (bf16) -> 16B vector stores ----
  const int region = (n0 >= 768) ? 2 : (n0 >= 384 ? 1 : 0);   // q/k/v, block-uniform
  const float scl = (region == 0) ? SCALEL2E : 1.0f;
  const float bias0 = bias[n0 + wn + lrow];
  const float bias1 = bias[n0 + wn + 16 + lrow];

#pragma unroll
  for (int half = 0; half < 2; ++half) {
    __syncthreads();
    if ((wv >> 1) == half) {
#pragma unroll
      for (int mi = 0; mi < 4; ++mi)
#pragma unroll
        for (int ni = 0; ni < 2; ++ni)
#pragma unroll
          for (int r = 0; r < 4; ++r) {
            int row = mi * 16 + lq * 4 + r;        // 0..63 within half
            int col = wn + ni * 16 + lrow;         // 0..63
            float val = (acc[mi][ni][r] + (ni ? bias1 : bias0)) * scl;
            ebuf[row * 72 + col] = f2bf(val);
          }
    }
    __syncthreads();
    if (region < 2) {
      unsigned short* dst = (region == 0) ? qc : kc;
      const int obase = n0 - region * 384;
#pragma unroll
      for (int i = 0; i < 2; ++i) {
        int id = tid + i * 256;                    // 0..511 = 64 rows x 8 chunks
        int row = id >> 3, cc = id & 7;
        uint4 val = *(const uint4*)&ebuf[row * 72 + cc * 8];
        int nrow = m0 + half * 64 + row;
        int b = nrow >> 12, nn = nrow & 4095;
        int o = obase + cc * 8;
        int h = o / 48, d = o - h * 48;            // 8-chunk never straddles h
        *(uint4*)&dst[((size_t)(b * 8 + h) * NTOK + nn) * HD + d] = val;
      }
    } else {
#pragma unroll
      for (int i = 0; i < 2; ++i) {
        int id = tid + i * 256;                    // 0..511 = 64 cols x 8 row-chunks
        int col = id & 63, rc = id >> 6;
        int r0 = rc * 8;
        ushort4 lo, hi;
        lo.x = ebuf[(r0 + 0) * 72 + col]; lo.y = ebuf[(r0 + 1) * 72 + col];
        lo.z = ebuf[(r0 + 2) * 72 + col]; lo.w = ebuf[(r0 + 3) * 72 + col];
        hi.x = ebuf[(r0 + 4) * 72 + col]; hi.y = ebuf[(r0 + 5) * 72 + col];
        hi.z = ebuf[(r0 + 6) * 72 + col]; hi.w = ebuf[(r0 + 7) * 72 + col];
        uint4 pk;
        pk.x = (unsigned int)lo.x | ((unsigned int)lo.y << 16);
        pk.y = (unsigned int)lo.z | ((unsigned int)lo.w << 16);
        pk.z = (unsigned int)hi.x | ((unsigned int)hi.y << 16);
        pk.w = (unsigned int)hi.z | ((unsigned int)hi.w << 16);
        int nrow = m0 + half * 64 + r0;
        int b = nrow >> 12;
        int o = n0 - 768 + col;
        *(uint4*)&v_t[((size_t)(b * DIM + o)) * NTOK + (nrow & 4095)] = pk;
      }
    }
  }
}

// ---------------- LePE: depthwise 3x3, coalesced output (writes out base) --
__global__ __launch_bounds__(256) void lepe_kernel(
    const unsigned short* __restrict__ v_t,
    const float* __restrict__ lw, const float* __restrict__ lb,
    float* __restrict__ out) {
  __shared__ __align__(16) unsigned short pl[16 * 648];
  const int cg = blockIdx.x;      // 0..23
  const int sy = blockIdx.y;      // 0..7
  const int b  = blockIdx.z;      // 0..1
  const int t = threadIdx.x;
  const int y0 = sy * 8;
#pragma unroll
  for (int i = 0; i < 5; ++i) {
    int id = t + i * 256;                      // 0..1279
    int c = id / 80, rem = id - c * 80;
    int row = rem >> 3, cx = rem & 7;
    int y = y0 - 1 + row;
    uint4 val = make_uint4(0u, 0u, 0u, 0u);
    if (y >= 0 && y < 64)
      val = *(const uint4*)(v_t + ((size_t)(b * DIM + cg * 16 + c)) * NTOK + y * 64 + cx * 8);
    *(uint4*)&pl[c * 648 + row * 64 + cx * 8] = val;
  }
  __syncthreads();
  const int c = t & 15, pg = t >> 4;
  const int cglob = cg * 16 + c;
  float w[9];
#pragma unroll
  for (int j = 0; j < 9; ++j) w[j] = lw[cglob * 9 + j];
  const float bias = lb[cglob];
  const unsigned short* base = &pl[c * 648];
  for (int i = 0; i < 32; ++i) {
    int p = pg * 32 + i;
    int lr = p >> 6, x = p & 63;
    float acc = bias;
#pragma unroll
    for (int ky = 0; ky < 3; ++ky)
#pragma unroll
      for (int kx = 0; kx < 3; ++kx) {
        int xx = x + kx - 1;
        if (xx >= 0 && xx < 64)
          acc += w[ky * 3 + kx] * bf2f(base[(lr + ky) * 64 + xx]);
      }
    out[((size_t)(b * NTOK + sy * 512 + p)) * DIM + cglob] = acc;
  }
}

// ---------------- flash attention: no shuffles, register-prefetch staging --
// block 256 = 2 kt-halves x 2 q-waves x 2 Q-sets (128 qrows/block).
// S^T = K*Q^T (lane owns its qrow). PV key order is PERMUTED per MFMA slot
// (k-slot j -> key 16u+4hh+(j&3)+8(j>>2)) so the A-frag is 4 consecutive P32
// words (no lane exchange) and B-frags are 2x ds_read_b64 from V.
// K stride 72 / V stride 68: bank-conflict-free (b128 & b64 floors).
// V row 48 = ones -> PV col 48 accumulates lsum for free.
// ALL reinterprets are by-value __builtin_bit_cast: R6's unions defeated SROA
// and spilled 330 MB to scratch — never take the address of a repack temp.
__global__ __launch_bounds__(256, 2) void attn_kernel(
    const unsigned short* __restrict__ qc,
    const unsigned short* __restrict__ kcg,
    const unsigned short* __restrict__ v_t,
    float* __restrict__ out) {
  __shared__ __align__(16) char smem[36864];
  unsigned short* Kl = (unsigned short*)smem;            // [2][64*72]
  unsigned short* Vl = (unsigned short*)(smem + 18432);  // [2][64*68]
  float* Lsum = (float*)(smem + 35840);                  // [2][128]
  float* Ol   = (float*)smem;                            // alias [128][48] epilogue

  const int tid = threadIdx.x;
  const int wv = tid >> 6, ln = tid & 63;
  const int kh = wv >> 1;          // kt-half
  const int wq = wv & 1;           // qrow group within each set
  const int l31 = ln & 31, hh = ln >> 5;
  const int th = tid & 127;        // thread id within half
  const int qb = blockIdx.x;       // 0..31  (128 qrows each)
  const int bh = blockIdx.y;
  const int b = bh >> 3, hd = bh & 7;

  unsigned short* Kh = Kl + kh * 4608;
  unsigned short* Vh = Vl + kh * 4352;

  // staging offsets (loop-invariant). K: 64 rows x 8 chunks (2 overfetch).
  int kwo[4], kgo[4], vwo[3], vgo[3];
#pragma unroll
  for (int i = 0; i < 4; ++i) {
    int idx = th + i * 128;                // 0..511
    int r = idx >> 3, cc = idx & 7;
    kwo[i] = r * 72 + cc * 8;
    kgo[i] = r * 48 + cc * 8;              // cc>=6 overfetch: never read back
  }
#pragma unroll
  for (int i = 0; i < 3; ++i) {
    int idx = th + i * 128;                // 0..383
    int vd = idx >> 3, vc = idx & 7;       // V: 48 rows x 8 chunks
    vwo[i] = vd * 68 + vc * 8;
    vgo[i] = vd * 4096 + vc * 8;
  }

  // V ones-row (row 48): PV output col 48 = sum_k P = lsum. Never re-written.
  if (th < 8) {
    uint4 one4 = make_uint4(0x3F803F80u, 0x3F803F80u, 0x3F803F80u, 0x3F803F80u);
    *(uint4*)&Vh[48 * 68 + th * 8] = one4;
  }

  // Q fragments: 2 sets x (lane's own qrow, 3 hd-chunks of 16)
  bf16x8 Qf[2][3];
#pragma unroll
  for (int set = 0; set < 2; ++set) {
    const int qrow = qb * 128 + set * 64 + wq * 32 + l31;
    const unsigned short* qp = qc + ((size_t)bh * NTOK + qrow) * HD + hh * 8;
#pragma unroll
    for (int hs = 0; hs < 3; ++hs)
      Qf[set][hs] = *(const bf16x8*)(qp + hs * 16);
  }

  f32x16 Oacc[2][2];
#pragma unroll
  for (int set = 0; set < 2; ++set)
#pragma unroll
    for (int dc = 0; dc < 2; ++dc)
#pragma unroll
      for (int r = 0; r < 16; ++r) Oacc[set][dc][r] = 0.f;

  const unsigned short* kbase = kcg + (size_t)bh * NTOK * HD;
  const unsigned short* vbase = v_t + ((size_t)b * DIM + hd * HD) * NTOK;

  // prologue: prefetch first tile into registers
  uint4 kreg0, kreg1, kreg2, kreg3, vreg0, vreg1, vreg2;
  {
    const unsigned short* kg = kbase + (size_t)(kh * 32) * 64 * HD;
    const unsigned short* vg = vbase + (kh * 32) * 64;
    kreg0 = *(const uint4*)(kg + kgo[0]);
    kreg1 = *(const uint4*)(kg + kgo[1]);
    kreg2 = *(const uint4*)(kg + kgo[2]);
    kreg3 = *(const uint4*)(kg + kgo[3]);
    vreg0 = *(const uint4*)(vg + vgo[0]);
    vreg1 = *(const uint4*)(vg + vgo[1]);
    vreg2 = *(const uint4*)(vg + vgo[2]);
  }

  for (int it = 0; it < 32; ++it) {
    __syncthreads();                       // prev compute done reading LDS
    *(uint4*)&Kh[kwo[0]] = kreg0;
    *(uint4*)&Kh[kwo[1]] = kreg1;
    *(uint4*)&Kh[kwo[2]] = kreg2;
    *(uint4*)&Kh[kwo[3]] = kreg3;
    *(uint4*)&Vh[vwo[0]] = vreg0;
    *(uint4*)&Vh[vwo[1]] = vreg1;
    *(uint4*)&Vh[vwo[2]] = vreg2;
    {                                      // issue next-tile loads (hidden under compute)
      int ktn = kh * 32 + ((it + 1) & 31); // wraps on last iter: in-bounds, same work
      const unsigned short* kg = kbase + (size_t)ktn * 64 * HD;
      const unsigned short* vg = vbase + ktn * 64;
      kreg0 = *(const uint4*)(kg + kgo[0]);
      kreg1 = *(const uint4*)(kg + kgo[1]);
      kreg2 = *(const uint4*)(kg + kgo[2]);
      kreg3 = *(const uint4*)(kg + kgo[3]);
      vreg0 = *(const uint4*)(vg + vgo[0]);
      vreg1 = *(const uint4*)(vg + vgo[1]);
      vreg2 = *(const uint4*)(vg + vgo[2]);
    }
    __syncthreads();                       // LDS tile visible

#pragma unroll
    for (int C = 0; C < 2; ++C) {
      // S^T = K * Q^T for both Q sets (3 K=16 steps, shared kf)
      f32x16 sA, sB;
#pragma unroll
      for (int r = 0; r < 16; ++r) { sA[r] = 0.f; sB[r] = 0.f; }
      const unsigned short* kr = &Kh[(C * 32 + l31) * 72 + hh * 8];
#pragma unroll
      for (int hs = 0; hs < 3; ++hs) {
        bf16x8 kf = *(const bf16x8*)(kr + hs * 16);
        sA = __builtin_amdgcn_mfma_f32_32x32x16_bf16(kf, Qf[0][hs], sA, 0, 0, 0);
        sB = __builtin_amdgcn_mfma_f32_32x32x16_bf16(kf, Qf[1][hs], sB, 0, 0, 0);
      }
      // exp2 + pack pairs: P[t8] = regs (2t8, 2t8+1) as bf16x2 (by value)
      unsigned int PA[8], PB[8];
#pragma unroll
      for (int t8 = 0; t8 < 8; ++t8) {
        float a0 = EXP2F(sA[2 * t8]);
        float a1 = EXP2F(sA[2 * t8 + 1]);
        PA[t8] = __builtin_amdgcn_perm(__float_as_uint(a1), __float_as_uint(a0),
                                       0x07060302u);
        float b0 = EXP2F(sB[2 * t8]);
        float b1 = EXP2F(sB[2 * t8 + 1]);
        PB[t8] = __builtin_amdgcn_perm(__float_as_uint(b1), __float_as_uint(b0),
                                       0x07060302u);
      }
      // O += P*V with permuted key order: A = 4 consecutive P words (bit_cast);
      // B slot j -> key C*32 + 16u + 4hh + (j&3) + 8(j>>2)  (groups g, g+2)
#pragma unroll
      for (int u = 0; u < 2; ++u) {
        bf16x8 pav0 = __builtin_bit_cast(bf16x8,
            make_uint4(PA[4 * u + 0], PA[4 * u + 1], PA[4 * u + 2], PA[4 * u + 3]));
        bf16x8 pav1 = __builtin_bit_cast(bf16x8,
            make_uint4(PB[4 * u + 0], PB[4 * u + 1], PB[4 * u + 2], PB[4 * u + 3]));
        const int goff = (C * 8 + 4 * u + hh) * 4;   // group start (shorts)
#pragma unroll
        for (int dc = 0; dc < 2; ++dc) {
          const int vrow = dc * 32 + l31;  // row 48 = ones (lsum); 49-63 discarded
          const unsigned short* vrp = &Vh[vrow * 68 + goff];
          uint2 g0 = *(const uint2*)(vrp);
          uint2 g2 = *(const uint2*)(vrp + 8);       // group g+2
          bf16x8 vfv = __builtin_bit_cast(bf16x8, make_uint4(g0.x, g0.y, g2.x, g2.y));
          Oacc[0][dc] = __builtin_amdgcn_mfma_f32_32x32x16_bf16(
              pav0, vfv, Oacc[0][dc], 0, 0, 0);
          Oacc[1][dc] = __builtin_amdgcn_mfma_f32_32x32x16_bf16(
              pav1, vfv, Oacc[1][dc], 0, 0, 0);
        }
      }
    }
  }

  // ---- epilogue: combine kt-halves through LDS, normalize, out += ----
  __syncthreads();
  if (l31 == 16) {
#pragma unroll
    for (int set = 0; set < 2; ++set)
#pragma unroll
      for (int r = 0; r < 16; ++r) {
        int qrb = set * 64 + wq * 32 + (r & 3) + 8 * (r >> 2) + 4 * hh;
        Lsum[kh * 128 + qrb] = Oacc[set][1][r];
      }
  }
  if (kh == 1) {
#pragma unroll
    for (int set = 0; set < 2; ++set)
#pragma unroll
      for (int r = 0; r < 16; ++r) {
        int qrb = set * 64 + wq * 32 + (r & 3) + 8 * (r >> 2) + 4 * hh;
        Ol[qrb * 48 + l31] = Oacc[set][0][r];
        if (l31 < 16) Ol[qrb * 48 + 32 + l31] = Oacc[set][1][r];
      }
  }
  __syncthreads();
  if (kh == 0) {
#pragma unroll
    for (int set = 0; set < 2; ++set)
#pragma unroll
      for (int r = 0; r < 16; ++r) {
        int qrb = set * 64 + wq * 32 + (r & 3) + 8 * (r >> 2) + 4 * hh;
        float linv = 1.0f / (Lsum[qrb] + Lsum[128 + qrb]);
        float* op = out + ((size_t)(b * NTOK + qb * 128 + qrb)) * DIM + hd * HD;
        op[l31] += (Oacc[set][0][r] + Ol[qrb * 48 + l31]) * linv;
        if (l31 < 16)
          op[32 + l31] += (Oacc[set][1][r] + Ol[qrb * 48 + 32 + l31]) * linv;
      }
  }
}

// ---------------------------------------------------------------------------
extern "C" void kernel_launch(void* const* d_in, const int* in_sizes, int n_in,
                              void* d_out, int out_size, void* d_ws, size_t ws_size,
                              hipStream_t stream) {
  const float* x      = (const float*)d_in[0];
  const float* qkv_w  = (const float*)d_in[1];
  const float* qkv_b  = (const float*)d_in[2];
  const float* lepe_w = (const float*)d_in[3];
  const float* lepe_b = (const float*)d_in[4];

  char* ws = (char*)d_ws;
  unsigned short* x_bf = (unsigned short*)(ws);
  unsigned short* w_bf = (unsigned short*)(ws + 6291456);
  unsigned short* qcp  = (unsigned short*)(ws + 7176192);
  unsigned short* kcp  = (unsigned short*)(ws + 13467648);
  unsigned short* v_t  = (unsigned short*)(ws + 19759104);
  float* out = (float*)d_out;

  prep_kernel<<<1024, 256, 0, stream>>>(x, qkv_w, x_bf, w_bf);
  qkv_gemm<<<dim3(64, 18), 256, 0, stream>>>(x_bf, w_bf, qkv_b, qcp, kcp, v_t);
  lepe_kernel<<<dim3(24, 8, 2), 256, 0, stream>>>(v_t, lepe_w, lepe_b, out);
  attn_kernel<<<dim3(32, 16), 256, 0, stream>>>(qcp, kcp, v_t, out);
}